// Round 4
// baseline (132.020 us; speedup 1.0000x reference)
//
#include <hip/hip_runtime.h>

#define LOG2E 1.4426950408889634f

typedef __attribute__((ext_vector_type(8))) short short8;
typedef __attribute__((ext_vector_type(16))) float f32x16;

__device__ __forceinline__ unsigned short f2bf(float f) {
  unsigned int u = __float_as_uint(f);
  u = (u + 0x7fffu + ((u >> 16) & 1u)) >> 16;   // RNE, finite inputs only
  return (unsigned short)u;
}

// ---------------------------------------------------------------------------
// Kernel 1 (merged): blocks 0..255   : f = X @ W^T + b  (fp32 SGEMM 128x128)
//                    blocks 256..2303: adj -> bitmask pack (ballot, 1 bit/edge)
// GEMM path emits ft (bf16 [b][n/16][h][c][n%16]) and s_src/s_dst (*LOG2E).
// Pack path writes bits[c] = ballot(adj[c*64 + lane] != 0), c = 0..524287.
// The pack's 134 MB HBM stream overlaps the GEMM's VALU work.
// ---------------------------------------------------------------------------
__global__ __launch_bounds__(256) void gat_k1(
    const float* __restrict__ X, const float* __restrict__ W,
    const float* __restrict__ bias, const float* __restrict__ a,
    const int* __restrict__ adj,
    unsigned short* __restrict__ ft, float* __restrict__ ssrc,
    float* __restrict__ sdst, unsigned long long* __restrict__ bits)
{
  if (blockIdx.x >= 256) {
    // ---------------- pack path ----------------
    const int pb = blockIdx.x - 256;                 // 0..2047
    const int gw = (pb << 2) + (threadIdx.x >> 6);   // global wave id, 8192 waves
    const int lane = threadIdx.x & 63;
    for (int c = gw; c < 524288; c += 8192) {
      const size_t base = ((size_t)c) << 6;
      int v = adj[base + lane];
      unsigned long long m = __ballot(v != 0);
      if (lane == 0) bits[c] = m;
    }
    return;
  }

  // ---------------- GEMM path ----------------
  __shared__ float Xs[8][128];
  __shared__ float Ws[8][128];
  const int tid = threadIdx.x;
  const int tx = tid & 15, ty = tid >> 4;
  const int m0 = (blockIdx.x >> 1) * 128;
  const int c0 = (blockIdx.x & 1) * 128;

  float acc[8][8];
#pragma unroll
  for (int r = 0; r < 8; ++r)
#pragma unroll
    for (int j = 0; j < 8; ++j) acc[r][j] = 0.f;

  const int lrow = tid >> 1;
  const int kk0 = (tid & 1) * 4;
  const float* Xp = X + (size_t)(m0 + lrow) * 256 + kk0;
  const float* Wp = W + (size_t)(c0 + lrow) * 256 + kk0;

  for (int kc = 0; kc < 256; kc += 8) {
    float4 xv = *(const float4*)(Xp + kc);
    float4 wv = *(const float4*)(Wp + kc);
    __syncthreads();
    Xs[kk0 + 0][lrow] = xv.x; Xs[kk0 + 1][lrow] = xv.y;
    Xs[kk0 + 2][lrow] = xv.z; Xs[kk0 + 3][lrow] = xv.w;
    Ws[kk0 + 0][lrow] = wv.x; Ws[kk0 + 1][lrow] = wv.y;
    Ws[kk0 + 2][lrow] = wv.z; Ws[kk0 + 3][lrow] = wv.w;
    __syncthreads();
#pragma unroll
    for (int kk = 0; kk < 8; ++kk) {
      float av[8], wv8[8];
#pragma unroll
      for (int r = 0; r < 8; ++r) av[r] = Xs[kk][ty * 8 + r];
#pragma unroll
      for (int j = 0; j < 8; ++j) wv8[j] = Ws[kk][tx * 8 + j];
#pragma unroll
      for (int r = 0; r < 8; ++r)
#pragma unroll
        for (int j = 0; j < 8; ++j) acc[r][j] = fmaf(av[r], wv8[j], acc[r][j]);
    }
  }

  const int b = m0 >> 11;
  const int nloc0 = (m0 & 2047) + ty * 8;
  const int cg0 = c0 + tx * 8;
  const int h = cg0 >> 6;
  const int cb = cg0 & 63;

  float bv[8], av_s[8], av_d[8];
#pragma unroll
  for (int j = 0; j < 8; ++j) {
    bv[j]   = bias[cg0 + j];
    av_s[j] = a[h * 128 + cb + j];
    av_d[j] = a[h * 128 + 64 + cb + j];
  }
#pragma unroll
  for (int r = 0; r < 8; ++r)
#pragma unroll
    for (int j = 0; j < 8; ++j) acc[r][j] += bv[j];

  const int jt = nloc0 >> 4;
  const int ni = nloc0 & 15;
#pragma unroll
  for (int j = 0; j < 8; ++j) {
    unsigned int u[4];
#pragma unroll
    for (int q = 0; q < 4; ++q) {
      unsigned int lo = f2bf(acc[2 * q + 0][j]);
      unsigned int hi = f2bf(acc[2 * q + 1][j]);
      u[q] = lo | (hi << 16);
    }
    size_t off = ((((size_t)b * 128 + jt) * 4 + h) * 64 + (cb + j)) * 16 + ni;
    *(uint4*)(ft + off) = make_uint4(u[0], u[1], u[2], u[3]);
  }

  float sp[8], dp[8];
#pragma unroll
  for (int r = 0; r < 8; ++r) {
    float s = 0.f, d = 0.f;
#pragma unroll
    for (int j = 0; j < 8; ++j) {
      s = fmaf(acc[r][j], av_s[j], s);
      d = fmaf(acc[r][j], av_d[j], d);
    }
    sp[r] = s; dp[r] = d;
  }
#pragma unroll
  for (int off = 1; off < 8; off <<= 1) {
#pragma unroll
    for (int r = 0; r < 8; ++r) {
      sp[r] += __shfl_xor(sp[r], off);
      dp[r] += __shfl_xor(dp[r], off);
    }
  }
  if ((tx & 7) == 0) {
    float* sb = ssrc + ((size_t)b * 4 + h) * 2048 + nloc0;
    float* db = sdst + ((size_t)b * 4 + h) * 2048 + nloc0;
#pragma unroll
    for (int r = 0; r < 8; ++r) { sb[r] = sp[r] * LOG2E; db[r] = dp[r] * LOG2E; }
  }
}

// ---------------------------------------------------------------------------
// Kernel 2: fused mask + leaky-relu + softmax + PV (bf16 MFMA 32x32x16)
// Grid 512 blocks (b = idx&7 XCD-pinned, itile = idx>>3, 32 i-rows).
// 512 thr = 8 waves = (head h, j-parity p). adj bits (8 KB) + s_dst (32 KB)
// staged in LDS at prologue; per step: one conflict-free ds_read_b32 for the
// mask word, broadcast sd reads, 4-deep register-prefetched ft (L2/L3).
// Zero barriers in the 64-step main loop.
// ---------------------------------------------------------------------------
__global__ __launch_bounds__(512, 4) void gat_k2(
    const void* __restrict__ bitsv, const unsigned short* __restrict__ ft,
    const float* __restrict__ ssrc, const float* __restrict__ sdst,
    float* __restrict__ out)
{
  __shared__ __align__(16) unsigned char lds[41216];  // sd 32KB | A 64x33 u32
  float* sd = (float*)lds;                            // [4][2048] f32
  unsigned* Aw = (unsigned*)(lds + 32768);            // [64][33] u32

  const int tid = threadIdx.x;
  const int b = blockIdx.x & 7;
  const int itile = blockIdx.x >> 3;     // 0..63
  const int i0 = itile * 32;
  const int w = tid >> 6;
  const int h = w >> 1;
  const int p = w & 1;
  const int lane = tid & 63;
  const int l31 = lane & 31;
  const int kh = lane >> 5;
  const int shamt = (2 * p + kh) * 8;    // byte select within mask word

  // ---- stage s_dst (32 KB contiguous) ----
  {
    const float4* src = (const float4*)(sdst + (size_t)b * 4 * 2048);
    float4* dst = (float4*)sd;
#pragma unroll
    for (int q = 0; q < 4; ++q) dst[tid + q * 512] = src[tid + q * 512];
  }
  // ---- stage adj bit words for rows i0..i0+31: A[word s][row] ----
  {
    const uint4* bsrc = (const uint4*)((const char*)bitsv +
                                       ((size_t)(b * 2048 + i0)) * 256);
    uint4 v = bsrc[tid];                       // 8 KB contiguous
    const int row = tid >> 4, w0 = (tid & 15) * 4;
    Aw[(w0 + 0) * 33 + row] = v.x;
    Aw[(w0 + 1) * 33 + row] = v.y;
    Aw[(w0 + 2) * 33 + row] = v.z;
    Aw[(w0 + 3) * 33 + row] = v.w;
  }
  const float si = ssrc[((size_t)b * 4 + h) * 2048 + i0 + l31];

  const unsigned short* ftb =
      ft + ((((size_t)b * 128 + p) * 4 + h) * 64 + l31) * 16 + kh * 8;
  const float* sdh = sd + h * 2048 + p * 16 + kh * 8;

  f32x16 acc0, acc1;
#pragma unroll
  for (int q = 0; q < 16; ++q) { acc0[q] = 0.f; acc1[q] = 0.f; }
  float lsum = 0.f;

  __syncthreads();

  uint4 f0a, f0b, f1a, f1b, f2a, f2b, f3a, f3b;

#define LOADF(s, fa, fb)                                          \
  {                                                               \
    const unsigned short* fp_ = ftb + (size_t)(s) * 8192;         \
    fa = *(const uint4*)fp_;                                      \
    fb = *(const uint4*)(fp_ + 512);                              \
  }

#define COMP(s, fa, fb)                                           \
  {                                                               \
    const unsigned wrd = Aw[(s) * 33 + l31];                      \
    const unsigned byte_ = (wrd >> shamt) & 0xffu;                \
    const float* tp_ = sdh + (s) * 32;                            \
    float4 t0_ = *(const float4*)tp_;                             \
    float4 t1_ = *(const float4*)(tp_ + 4);                       \
    float tj_[8] = {t0_.x, t0_.y, t0_.z, t0_.w,                   \
                    t1_.x, t1_.y, t1_.z, t1_.w};                  \
    float e_[8];                                                  \
    _Pragma("unroll")                                             \
    for (int q = 0; q < 8; ++q) {                                 \
      float x_ = si + tj_[q];                                     \
      float y_ = fmaxf(x_, 0.2f * x_);                            \
      float ev_ = __builtin_amdgcn_exp2f(y_);                     \
      ev_ = (byte_ & (1u << q)) ? ev_ : 0.f;                      \
      e_[q] = ev_;                                                \
      lsum += ev_;                                                \
    }                                                             \
    union { unsigned u[4]; short8 v; } af_;                       \
    _Pragma("unroll")                                             \
    for (int q2 = 0; q2 < 4; ++q2) {                              \
      unsigned r_;                                                \
      asm("v_cvt_pk_bf16_f32 %0, %1, %2"                          \
          : "=v"(r_) : "v"(e_[2 * q2]), "v"(e_[2 * q2 + 1]));     \
      af_.u[q2] = r_;                                             \
    }                                                             \
    union { uint4 q; short8 v; } b0_, b1_;                        \
    b0_.q = fa; b1_.q = fb;                                       \
    acc0 = __builtin_amdgcn_mfma_f32_32x32x16_bf16(af_.v, b0_.v, acc0, 0, 0, 0); \
    acc1 = __builtin_amdgcn_mfma_f32_32x32x16_bf16(af_.v, b1_.v, acc1, 0, 0, 0); \
  }

  LOADF(0, f0a, f0b)
  LOADF(1, f1a, f1b)
  LOADF(2, f2a, f2b)
  LOADF(3, f3a, f3b)

  for (int s = 0; s < 64; s += 4) {
    const int n0 = (s + 4 < 64) ? s + 4 : 63;
    const int n1 = (s + 5 < 64) ? s + 5 : 63;
    const int n2 = (s + 6 < 64) ? s + 6 : 63;
    const int n3 = (s + 7 < 64) ? s + 7 : 63;
    COMP(s + 0, f0a, f0b) LOADF(n0, f0a, f0b)
    COMP(s + 1, f1a, f1b) LOADF(n1, f1a, f1b)
    COMP(s + 2, f2a, f2b) LOADF(n2, f2a, f2b)
    COMP(s + 3, f3a, f3b) LOADF(n3, f3a, f3b)
  }
#undef LOADF
#undef COMP

  // ---- epilogue: combine p=0/p=1 partials, normalize, store ----
  float lsum2 = lsum + __shfl_xor(lsum, 32);   // fold kh halves
  float* ep = (float*)lds;                      // [4][32][64] f32 = 32 KB
  float* el = (float*)(lds + 32768);            // [4][32] f32
  __syncthreads();                              // everyone done reading sd/Aw
  if (p == 1) {
#pragma unroll
    for (int reg = 0; reg < 16; ++reg) {
      const int row = (reg & 3) + 8 * (reg >> 2) + 4 * kh;
      ep[(h * 32 + row) * 64 + l31]      = acc0[reg];
      ep[(h * 32 + row) * 64 + l31 + 32] = acc1[reg];
    }
    if (lane < 32) el[h * 32 + l31] = lsum2;
  }
  __syncthreads();
  if (p == 0) {
    const float L = lsum2 + el[h * 32 + l31];
    const float rinv = 1.0f / L;
    float* ob = out + ((size_t)(b * 2048 + i0)) * 256 + h * 64;
#pragma unroll
    for (int reg = 0; reg < 16; ++reg) {
      const int row = (reg & 3) + 8 * (reg >> 2) + 4 * kh;
      const float ri = __shfl(rinv, row);
      const float o0 = (acc0[reg] + ep[(h * 32 + row) * 64 + l31]) * ri;
      const float o1 = (acc1[reg] + ep[(h * 32 + row) * 64 + l31 + 32]) * ri;
      ob[(size_t)row * 256 + l31]      = o0;
      ob[(size_t)row * 256 + l31 + 32] = o1;
    }
  }
}

// ---------------------------------------------------------------------------
extern "C" void kernel_launch(void* const* d_in, const int* in_sizes, int n_in,
                              void* d_out, int out_size, void* d_ws, size_t ws_size,
                              hipStream_t stream) {
  const float* X    = (const float*)d_in[0];   // (8,2048,256) f32
  const int*   adj  = (const int*)d_in[1];     // (8,2048,2048) i32
  const float* W    = (const float*)d_in[2];   // (256,256) f32
  const float* bias = (const float*)d_in[3];   // (256,) f32
  const float* a    = (const float*)d_in[4];   // (4,128) f32
  float* out = (float*)d_out;

  unsigned short* ft = (unsigned short*)d_ws;                        // 8 MB bf16
  float* ssrc = (float*)((char*)d_ws + 8388608);                     // 256 KB
  float* sdst = ssrc + 8 * 4 * 2048;                                 // 256 KB
  unsigned long long* bits =
      (unsigned long long*)((char*)d_ws + 8912896);                  // 4 MB

  gat_k1<<<dim3(2304, 1, 1), 256, 0, stream>>>(X, W, bias, a, adj,
                                               ft, ssrc, sdst, bits);
  gat_k2<<<dim3(512, 1, 1), 512, 0, stream>>>(bits, ft, ssrc, sdst, out);
}

// Round 5
// 103.991 us; speedup vs baseline: 1.2695x; 1.2695x over previous
//
#include <hip/hip_runtime.h>

#define LOG2E 1.4426950408889634f

typedef __attribute__((ext_vector_type(8))) short short8;
typedef __attribute__((ext_vector_type(16))) float f32x16;

__device__ __forceinline__ unsigned short f2bf(float f) {
  unsigned int u = __float_as_uint(f);
  u = (u + 0x7fffu + ((u >> 16) & 1u)) >> 16;   // RNE, finite inputs only
  return (unsigned short)u;
}

// ---------------------------------------------------------------------------
// Kernel 1: f = X @ W^T + b  (fp32 SGEMM, 128x128 tile, 8x8/thread)
// Emits: ft (bf16, layout [b][n/16][h][c][n%16]) and s_src/s_dst ([b][h][n],
// f32, PRE-SCALED by log2(e) so k2 can use raw v_exp_f32).
// ---------------------------------------------------------------------------
__global__ __launch_bounds__(256) void gat_k1(
    const float* __restrict__ X, const float* __restrict__ W,
    const float* __restrict__ bias, const float* __restrict__ a,
    unsigned short* __restrict__ ft, float* __restrict__ ssrc,
    float* __restrict__ sdst)
{
  __shared__ float Xs[8][128];
  __shared__ float Ws[8][128];
  const int tid = threadIdx.x;
  const int tx = tid & 15, ty = tid >> 4;
  const int m0 = blockIdx.x * 128;
  const int c0 = blockIdx.y * 128;

  float acc[8][8];
#pragma unroll
  for (int r = 0; r < 8; ++r)
#pragma unroll
    for (int j = 0; j < 8; ++j) acc[r][j] = 0.f;

  const int lrow = tid >> 1;
  const int kk0 = (tid & 1) * 4;
  const float* Xp = X + (size_t)(m0 + lrow) * 256 + kk0;
  const float* Wp = W + (size_t)(c0 + lrow) * 256 + kk0;

  for (int kc = 0; kc < 256; kc += 8) {
    float4 xv = *(const float4*)(Xp + kc);
    float4 wv = *(const float4*)(Wp + kc);
    __syncthreads();
    Xs[kk0 + 0][lrow] = xv.x; Xs[kk0 + 1][lrow] = xv.y;
    Xs[kk0 + 2][lrow] = xv.z; Xs[kk0 + 3][lrow] = xv.w;
    Ws[kk0 + 0][lrow] = wv.x; Ws[kk0 + 1][lrow] = wv.y;
    Ws[kk0 + 2][lrow] = wv.z; Ws[kk0 + 3][lrow] = wv.w;
    __syncthreads();
#pragma unroll
    for (int kk = 0; kk < 8; ++kk) {
      float av[8], wv8[8];
#pragma unroll
      for (int r = 0; r < 8; ++r) av[r] = Xs[kk][ty * 8 + r];
#pragma unroll
      for (int j = 0; j < 8; ++j) wv8[j] = Ws[kk][tx * 8 + j];
#pragma unroll
      for (int r = 0; r < 8; ++r)
#pragma unroll
        for (int j = 0; j < 8; ++j) acc[r][j] = fmaf(av[r], wv8[j], acc[r][j]);
    }
  }

  const int b = m0 >> 11;
  const int nloc0 = (m0 & 2047) + ty * 8;
  const int cg0 = c0 + tx * 8;
  const int h = cg0 >> 6;
  const int cb = cg0 & 63;

  float bv[8], av_s[8], av_d[8];
#pragma unroll
  for (int j = 0; j < 8; ++j) {
    bv[j]   = bias[cg0 + j];
    av_s[j] = a[h * 128 + cb + j];
    av_d[j] = a[h * 128 + 64 + cb + j];
  }
#pragma unroll
  for (int r = 0; r < 8; ++r)
#pragma unroll
    for (int j = 0; j < 8; ++j) acc[r][j] += bv[j];

  const int jt = nloc0 >> 4;
  const int ni = nloc0 & 15;
#pragma unroll
  for (int j = 0; j < 8; ++j) {
    unsigned int u[4];
#pragma unroll
    for (int q = 0; q < 4; ++q) {
      unsigned int lo = f2bf(acc[2 * q + 0][j]);
      unsigned int hi = f2bf(acc[2 * q + 1][j]);
      u[q] = lo | (hi << 16);
    }
    size_t off = ((((size_t)b * 128 + jt) * 4 + h) * 64 + (cb + j)) * 16 + ni;
    *(uint4*)(ft + off) = make_uint4(u[0], u[1], u[2], u[3]);
  }

  float sp[8], dp[8];
#pragma unroll
  for (int r = 0; r < 8; ++r) {
    float s = 0.f, d = 0.f;
#pragma unroll
    for (int j = 0; j < 8; ++j) {
      s = fmaf(acc[r][j], av_s[j], s);
      d = fmaf(acc[r][j], av_d[j], d);
    }
    sp[r] = s; dp[r] = d;
  }
#pragma unroll
  for (int off = 1; off < 8; off <<= 1) {
#pragma unroll
    for (int r = 0; r < 8; ++r) {
      sp[r] += __shfl_xor(sp[r], off);
      dp[r] += __shfl_xor(dp[r], off);
    }
  }
  if ((tx & 7) == 0) {
    float* sb = ssrc + ((size_t)b * 4 + h) * 2048 + nloc0;
    float* db = sdst + ((size_t)b * 4 + h) * 2048 + nloc0;
#pragma unroll
    for (int r = 0; r < 8; ++r) { sb[r] = sp[r] * LOG2E; db[r] = dp[r] * LOG2E; }
  }
}

// ---------------------------------------------------------------------------
// Kernel 2: fused mask + leaky-relu + softmax + PV (bf16 MFMA 32x32x16)
// Grid 512 blocks (b = idx&7 XCD-pinned, itile = idx>>3, 32 i-rows).
// 512 thr = 8 waves = (head h, j-parity p).
// PROLOGUE: stream this block's 256 KB of adj (each element read exactly once
// grid-wide), pack thread-locally to 16-bit masks, store into LDS Aw[s][row].
// MAIN LOOP: zero barriers; mask = one conflict-free ds_read_b32; sd reads
// broadcast; ft 4-deep register-prefetched (L2/L3-resident).
// ---------------------------------------------------------------------------
__global__ __launch_bounds__(512, 4) void gat_k2(
    const int* __restrict__ adj, const unsigned short* __restrict__ ft,
    const float* __restrict__ ssrc, const float* __restrict__ sdst,
    float* __restrict__ out)
{
  __shared__ __align__(16) unsigned char lds[41216];  // sd 32KB | Aw 64x33 u32
  float* sd = (float*)lds;                            // [4][2048] f32
  unsigned* Aw = (unsigned*)(lds + 32768);            // [64][33] u32

  const int tid = threadIdx.x;
  const int b = blockIdx.x & 7;
  const int itile = blockIdx.x >> 3;     // 0..63
  const int i0 = itile * 32;
  const int w = tid >> 6;
  const int h = w >> 1;
  const int p = w & 1;
  const int lane = tid & 63;
  const int l31 = lane & 31;
  const int kh = lane >> 5;
  const int shamt = (2 * p + kh) * 8;    // byte select within mask word

  // ---- stage s_dst (32 KB contiguous) ----
  {
    const float4* src = (const float4*)(sdst + (size_t)b * 4 * 2048);
    float4* dst = (float4*)sd;
#pragma unroll
    for (int q = 0; q < 4; ++q) dst[tid + q * 512] = src[tid + q * 512];
  }
  // ---- stream adj rows i0..i0+31 (256 KB), pack -> Aw[s][row] ----
  {
    const int* abase = adj + (size_t)b * 2048 * 2048 + (size_t)i0 * 2048;
    unsigned short* dst16 = (unsigned short*)Aw;
#pragma unroll
    for (int k = 0; k < 8; ++k) {
      const int idx = k * 512 + tid;          // [0,4096): wave reads 4KB strip
      const int r = idx >> 7;                 // row 0..31
      const int s16 = idx & 127;              // 16-j group
      const int4* ap = (const int4*)(abase + (size_t)r * 2048 + s16 * 16);
      int4 v0 = ap[0], v1 = ap[1], v2 = ap[2], v3 = ap[3];
      int vv[16] = {v0.x, v0.y, v0.z, v0.w, v1.x, v1.y, v1.z, v1.w,
                    v2.x, v2.y, v2.z, v2.w, v3.x, v3.y, v3.z, v3.w};
      unsigned m = 0;
#pragma unroll
      for (int i = 0; i < 16; ++i) m |= (vv[i] ? 1u : 0u) << i;
      dst16[(((s16 >> 1) * 33) + r) * 2 + (s16 & 1)] = (unsigned short)m;
    }
  }
  const float si = ssrc[((size_t)b * 4 + h) * 2048 + i0 + l31];

  const unsigned short* ftb =
      ft + ((((size_t)b * 128 + p) * 4 + h) * 64 + l31) * 16 + kh * 8;
  const float* sdh = sd + h * 2048 + p * 16 + kh * 8;

  f32x16 acc0, acc1;
#pragma unroll
  for (int q = 0; q < 16; ++q) { acc0[q] = 0.f; acc1[q] = 0.f; }
  float lsum = 0.f;

  __syncthreads();

  uint4 f0a, f0b, f1a, f1b, f2a, f2b, f3a, f3b;

#define LOADF(s, fa, fb)                                          \
  {                                                               \
    const unsigned short* fp_ = ftb + (size_t)(s) * 8192;         \
    fa = *(const uint4*)fp_;                                      \
    fb = *(const uint4*)(fp_ + 512);                              \
  }

#define COMP(s, fa, fb)                                           \
  {                                                               \
    const unsigned wrd = Aw[(s) * 33 + l31];                      \
    const unsigned byte_ = (wrd >> shamt) & 0xffu;                \
    const float* tp_ = sdh + (s) * 32;                            \
    float4 t0_ = *(const float4*)tp_;                             \
    float4 t1_ = *(const float4*)(tp_ + 4);                       \
    float tj_[8] = {t0_.x, t0_.y, t0_.z, t0_.w,                   \
                    t1_.x, t1_.y, t1_.z, t1_.w};                  \
    float e_[8];                                                  \
    _Pragma("unroll")                                             \
    for (int q = 0; q < 8; ++q) {                                 \
      float x_ = si + tj_[q];                                     \
      float y_ = fmaxf(x_, 0.2f * x_);                            \
      float ev_ = __builtin_amdgcn_exp2f(y_);                     \
      ev_ = (byte_ & (1u << q)) ? ev_ : 0.f;                      \
      e_[q] = ev_;                                                \
      lsum += ev_;                                                \
    }                                                             \
    union { unsigned u[4]; short8 v; } af_;                       \
    _Pragma("unroll")                                             \
    for (int q2 = 0; q2 < 4; ++q2) {                              \
      unsigned r_;                                                \
      asm("v_cvt_pk_bf16_f32 %0, %1, %2"                          \
          : "=v"(r_) : "v"(e_[2 * q2]), "v"(e_[2 * q2 + 1]));     \
      af_.u[q2] = r_;                                             \
    }                                                             \
    union { uint4 q; short8 v; } b0_, b1_;                        \
    b0_.q = fa; b1_.q = fb;                                       \
    acc0 = __builtin_amdgcn_mfma_f32_32x32x16_bf16(af_.v, b0_.v, acc0, 0, 0, 0); \
    acc1 = __builtin_amdgcn_mfma_f32_32x32x16_bf16(af_.v, b1_.v, acc1, 0, 0, 0); \
  }

  LOADF(0, f0a, f0b)
  LOADF(1, f1a, f1b)
  LOADF(2, f2a, f2b)
  LOADF(3, f3a, f3b)

  for (int s = 0; s < 64; s += 4) {
    const int n0 = (s + 4 < 64) ? s + 4 : 63;
    const int n1 = (s + 5 < 64) ? s + 5 : 63;
    const int n2 = (s + 6 < 64) ? s + 6 : 63;
    const int n3 = (s + 7 < 64) ? s + 7 : 63;
    COMP(s + 0, f0a, f0b) LOADF(n0, f0a, f0b)
    COMP(s + 1, f1a, f1b) LOADF(n1, f1a, f1b)
    COMP(s + 2, f2a, f2b) LOADF(n2, f2a, f2b)
    COMP(s + 3, f3a, f3b) LOADF(n3, f3a, f3b)
  }
#undef LOADF
#undef COMP

  // ---- epilogue: combine p=0/p=1 partials, normalize, store ----
  float lsum2 = lsum + __shfl_xor(lsum, 32);   // fold kh halves
  float* ep = (float*)lds;                      // [4][32][64] f32 = 32 KB
  float* el = (float*)(lds + 32768);            // [4][32] f32
  __syncthreads();                              // everyone done reading sd/Aw
  if (p == 1) {
#pragma unroll
    for (int reg = 0; reg < 16; ++reg) {
      const int row = (reg & 3) + 8 * (reg >> 2) + 4 * kh;
      ep[(h * 32 + row) * 64 + l31]      = acc0[reg];
      ep[(h * 32 + row) * 64 + l31 + 32] = acc1[reg];
    }
    if (lane < 32) el[h * 32 + l31] = lsum2;
  }
  __syncthreads();
  if (p == 0) {
    const float L = lsum2 + el[h * 32 + l31];
    const float rinv = 1.0f / L;
    float* ob = out + ((size_t)(b * 2048 + i0)) * 256 + h * 64;
#pragma unroll
    for (int reg = 0; reg < 16; ++reg) {
      const int row = (reg & 3) + 8 * (reg >> 2) + 4 * kh;
      const float ri = __shfl(rinv, row);
      const float o0 = (acc0[reg] + ep[(h * 32 + row) * 64 + l31]) * ri;
      const float o1 = (acc1[reg] + ep[(h * 32 + row) * 64 + l31 + 32]) * ri;
      ob[(size_t)row * 256 + l31]      = o0;
      ob[(size_t)row * 256 + l31 + 32] = o1;
    }
  }
}

// ---------------------------------------------------------------------------
extern "C" void kernel_launch(void* const* d_in, const int* in_sizes, int n_in,
                              void* d_out, int out_size, void* d_ws, size_t ws_size,
                              hipStream_t stream) {
  const float* X    = (const float*)d_in[0];   // (8,2048,256) f32
  const int*   adj  = (const int*)d_in[1];     // (8,2048,2048) i32
  const float* W    = (const float*)d_in[2];   // (256,256) f32
  const float* bias = (const float*)d_in[3];   // (256,) f32
  const float* a    = (const float*)d_in[4];   // (4,128) f32
  float* out = (float*)d_out;

  unsigned short* ft = (unsigned short*)d_ws;                    // 8 MB bf16
  float* ssrc = (float*)((char*)d_ws + 8388608);                 // 256 KB
  float* sdst = ssrc + 8 * 4 * 2048;                             // 256 KB

  gat_k1<<<dim3(128, 2, 1), 256, 0, stream>>>(X, W, bias, a, ft, ssrc, sdst);
  gat_k2<<<dim3(512, 1, 1), 512, 0, stream>>>(adj, ft, ssrc, sdst, out);
}